// Round 17
// baseline (209.956 us; speedup 1.0000x reference)
//
#include <hip/hip_runtime.h>
#include <math.h>

#define NB 4
#define C 96
#define C3 288
#define NH 8
#define CHD 12
#define HT 160
#define WD 160
#define HW 25600

typedef unsigned short u16;
typedef unsigned int   u32;
typedef __bf16 bf16x8 __attribute__((ext_vector_type(8)));
typedef float  f32x4  __attribute__((ext_vector_type(4)));

__device__ __forceinline__ float gelu_f(float x){
    return 0.5f * x * (1.0f + erff(x * 0.7071067811865475f));
}
__device__ __forceinline__ float sigmoid_f(float x){
    return 1.0f / (1.0f + expf(-x));
}
__device__ __forceinline__ u16 f2bf(float x){
    union { float f; u32 u; } v; v.f = x;
    u32 r = v.u + 0x7FFFu + ((v.u >> 16) & 1u);
    return (u16)(r >> 16);
}
__device__ __forceinline__ float bf2f(u16 s){
    union { u32 u; float f; } v; v.u = ((u32)s) << 16;
    return v.f;
}

// ---------------- K0: per-(b,c) spatial sums of x + bf16 copy of x ----------
__global__ __launch_bounds__(256) void k0_xsum(const float* __restrict__ x,
                                               float* __restrict__ xsum,
                                               u16* __restrict__ xb){
    int bc = blockIdx.x;                       // 0..383
    const float4* p4 = (const float4*)(x + (size_t)bc * HW);
    u32* xo = (u32*)(xb + (size_t)bc * HW);
    float s = 0.f;
    for (int i = threadIdx.x; i < HW/4; i += 256){
        float4 v = p4[i];
        s += (v.x + v.y) + (v.z + v.w);
        xo[i*2]   = (u32)f2bf(v.x) | ((u32)f2bf(v.y) << 16);
        xo[i*2+1] = (u32)f2bf(v.z) | ((u32)f2bf(v.w) << 16);
    }
    __shared__ float red[256];
    red[threadIdx.x] = s;
    __syncthreads();
    for (int off = 128; off > 0; off >>= 1){
        if (threadIdx.x < off) red[threadIdx.x] += red[threadIdx.x + off];
        __syncthreads();
    }
    if (threadIdx.x == 0) xsum[bc] = red[0];
}

// ---------------- K1: per-batch tiny math (one block per batch) --------------
__global__ void k1_small(const float* __restrict__ spectral, const float* __restrict__ xsum,
                         const float* __restrict__ w_se1, const float* __restrict__ b_se1,
                         const float* __restrict__ w_se2, const float* __restrict__ b_se2,
                         const float* __restrict__ w_saw1, const float* __restrict__ b_saw1,
                         const float* __restrict__ w_saw2, const float* __restrict__ b_saw2,
                         const float* __restrict__ w_sgp, const float* __restrict__ b_sgp,
                         float* __restrict__ swg, float* __restrict__ esgg){
    __shared__ float spec[96];
    __shared__ float h1[192];
    __shared__ float cm_s;
    __shared__ float g1[9][24];
    __shared__ float saw[8];
    __shared__ float redbuf[96];
    int t = threadIdx.x;
    int b = blockIdx.x;
    if (t < 96) spec[t] = spectral[b*96 + t];
    __syncthreads();
    if (t < 192){
        float a = b_se1[t];
        for (int c = 0; c < 96; c++) a += spec[c] * w_se1[t*96 + c];
        h1[t] = gelu_f(a);
    }
    __syncthreads();
    if (t < 96){
        float a = b_se2[t];
        for (int j = 0; j < 192; j++) a += h1[j] * w_se2[t*192 + j];
        float s = sigmoid_f(a);
        swg[b*96 + t] = s;
        redbuf[t] = s * xsum[b*96 + t];
    }
    __syncthreads();
    if (t == 0){
        float cs = 0.f;
        for (int c = 0; c < 96; c++) cs += redbuf[c];
        cm_s = cs / (96.0f * (float)HW);
    }
    __syncthreads();
    float cm = cm_s;
    if (t < 9*24){
        int cat = t / 24, ch = t % 24;
        int ti = cat / 3, tj = cat % 3;
        float S = 0.f;
        for (int ki = 0; ki < 3; ki++){
            if (ti == 0 && ki == 0) continue;
            if (ti == 2 && ki == 2) continue;
            for (int kj = 0; kj < 3; kj++){
                if (tj == 0 && kj == 0) continue;
                if (tj == 2 && kj == 2) continue;
                S += w_saw1[ch*9 + ki*3 + kj];
            }
        }
        g1[cat][ch] = gelu_f(cm * S + b_saw1[ch]);
    }
    __syncthreads();
    if (t < 8){
        float acc = 0.f;
        const float cnt[3] = {1.f, 158.f, 1.f};
        for (int cat = 0; cat < 9; cat++){
            float a = b_saw2[t];
            for (int ch = 0; ch < 24; ch++) a += w_saw2[t*24 + ch] * g1[cat][ch];
            acc += cnt[cat/3] * cnt[cat%3] * sigmoid_f(a);
        }
        saw[t] = acc / (float)HW;
    }
    __syncthreads();
    if (t < 96){
        float a = b_sgp[t];
        for (int j = 0; j < 96; j++) a += spec[j] * w_sgp[t*96 + j];
        esgg[b*96 + t] = a * saw[t/12];
    }
}

// ---------------- K1w: bake weffb = bf16(w_qkv * sw[b]) ----------------------
__global__ __launch_bounds__(256) void k1w_weff(const float* __restrict__ w_qkv,
                                                const float* __restrict__ swg,
                                                u16* __restrict__ weffb){
    int b = blockIdx.x;
    int i = blockIdx.y * 256 + threadIdx.x;     // 0..27647
    float w = w_qkv[i] * swg[b*96 + (i % 96)];
    weffb[(size_t)b*C3*96 + i] = f2bf(w);
}

// ---------------- K3w: precompute k3's structured A-fragment table -----------
__global__ __launch_bounds__(256) void k3w_atab(const float* __restrict__ w_fc,
                                                uint4* __restrict__ atab){
    for (int idx = threadIdx.x; idx < 63*64; idx += 256){
        int ct = idx / (9*64), rem = idx % (9*64);
        int kk = rem / 64, lane = rem % 64;
        int lr = lane & 15, lk = lane >> 4;
        int coA = ct*16 + lr;
        int dA = coA / 9;
        int oA = coA - dA*9;
        int base = kk*32 + lk*8;
        int bm = base % 12;
        int slot = dA - bm; slot += (slot < 0) ? 12 : 0;
        int j = base + slot;
        float wvl = (coA < 108 && slot < 8) ? w_fc[oA*24 + j/12] : 0.f;
        u32 pk = ((u32)f2bf(wvl)) << ((slot & 1) * 16);
        int sh = slot >> 1;
        uint4 a;
        a.x = (sh == 0) ? pk : 0u;
        a.y = (sh == 1) ? pk : 0u;
        a.z = (sh == 2) ? pk : 0u;
        a.w = (sh == 3) ? pk : 0u;
        atab[idx] = a;
    }
}

// ---------------- K2a: MFMA 1x1 conv, full 288 oc per block ------------------
__global__ __launch_bounds__(384) void k2a_mfma(const u16* __restrict__ xb,
                                                const u16* __restrict__ weffb,
                                                u16* __restrict__ Y,
                                                int bbase, long ystride){
    int b   = bbase + blockIdx.y;
    int px0 = blockIdx.x * 64;
    __shared__ __align__(16) u16 Xl[64*128];
    int t = threadIdx.x;
    const u32* xsrc = (const u32*)(xb + (size_t)b*C*HW + px0);
    for (int i = t; i < 96*32; i += 384){
        int c = i >> 5, pq = i & 31;
        u32 v = xsrc[(size_t)c*(HW/2) + pq];
        int slot = (((c >> 3) ^ (pq & 7)) << 3) + (c & 7);
        Xl[(2*pq)*128 + slot]     = (u16)(v & 0xffffu);
        Xl[(2*pq+1)*128 + slot]   = (u16)(v >> 16);
    }
    int wid = t >> 6, lane = t & 63;
    int lr = lane & 15, lk = lane >> 4;
    union U { uint4 q; bf16x8 v; };
    bf16x8 afr[3][3];
    const u16* wb = weffb + (size_t)b*C3*96;
    #pragma unroll
    for (int og = 0; og < 3; og++){
        int oc = og*96 + wid*16 + lr;
        #pragma unroll
        for (int kk = 0; kk < 3; kk++){
            U u; u.q = *(const uint4*)(wb + (size_t)oc*96 + kk*32 + lk*8);
            afr[og][kk] = u.v;
        }
    }
    __syncthreads();
    u16* Yb = Y + (size_t)blockIdx.y * ystride;
    #pragma unroll
    for (int sub = 0; sub < 4; sub++){
        int px = sub*16 + lr;
        int key = (px >> 1) & 7;
        bf16x8 bfr[3];
        #pragma unroll
        for (int kk = 0; kk < 3; kk++){
            int gs = (kk*4 + lk) ^ key;
            U u; u.q = *(const uint4*)(&Xl[px*128 + gs*8]);
            bfr[kk] = u.v;
        }
        #pragma unroll
        for (int og = 0; og < 3; og++){
            f32x4 acc = (f32x4){0.f,0.f,0.f,0.f};
            #pragma unroll
            for (int kk = 0; kk < 3; kk++)
                acc = __builtin_amdgcn_mfma_f32_16x16x32_bf16(afr[og][kk], bfr[kk], acc, 0, 0, 0);
            #pragma unroll
            for (int r = 0; r < 4; r++){
                int oc = og*96 + wid*16 + lk*4 + r;
                Yb[(size_t)oc*HW + px0 + sub*16 + lr] = f2bf(acc[r]);
            }
        }
    }
}

// ---------------- K2b: 3x3 depthwise, 16-row tiles, uint4 staging ------------
// tile col = input col + 4 (cols 3 / 164 are the zero halo). Each thread
// computes 8 px (one uint4 store) with 12 LDS ops per window.
__global__ __launch_bounds__(256) void k2b_dw(const u16* __restrict__ Y,
                                              const float* __restrict__ w_dw,
                                              u16* __restrict__ qkv,
                                              int bbase, long ystride){
    int b  = bbase + blockIdx.z;
    int ch = blockIdx.y;
    int r0 = blockIdx.x * 16;                  // 10 x-blocks
    __shared__ float tile[18][168];
    const u16* Yc = Y + (size_t)blockIdx.z*ystride + (size_t)ch*HW;
    int t = threadIdx.x;
    if (t < 18){ tile[t][3] = 0.f; tile[t][164] = 0.f; }
    for (int i = t; i < 18*20; i += 256){
        int r = i / 20, q = i % 20;
        int gr = r0 + r - 1;
        uint4 v = make_uint4(0,0,0,0);
        if (gr >= 0 && gr < HT) v = *(const uint4*)(Yc + gr*WD + q*8);
        float* dst = &tile[r][4 + q*8];
        float4 f0 = make_float4(bf2f((u16)(v.x & 0xffffu)), bf2f((u16)(v.x >> 16)),
                                bf2f((u16)(v.y & 0xffffu)), bf2f((u16)(v.y >> 16)));
        float4 f1 = make_float4(bf2f((u16)(v.z & 0xffffu)), bf2f((u16)(v.z >> 16)),
                                bf2f((u16)(v.w & 0xffffu)), bf2f((u16)(v.w >> 16)));
        *(float4*)(dst)     = f0;
        *(float4*)(dst + 4) = f1;
    }
    float w[9];
    #pragma unroll
    for (int k = 0; k < 9; k++) w[k] = w_dw[ch*9 + k];
    __syncthreads();
    u16* qc = qkv + ((size_t)b*C3 + ch)*HW + r0*WD;
    for (int i = t; i < 320; i += 256){
        int r = i / 20, q = i % 20;            // out row (0..15), col group
        float o[8];
        #pragma unroll
        for (int p = 0; p < 8; p++) o[p] = 0.f;
        #pragma unroll
        for (int ki = 0; ki < 3; ki++){
            const float* row = &tile[r + ki][q*8];
            float rw[10];
            rw[0] = row[3];
            float4 A = *(const float4*)(row + 4);
            float4 B = *(const float4*)(row + 8);
            rw[1]=A.x; rw[2]=A.y; rw[3]=A.z; rw[4]=A.w;
            rw[5]=B.x; rw[6]=B.y; rw[7]=B.z; rw[8]=B.w;
            rw[9] = row[12];
            #pragma unroll
            for (int kj = 0; kj < 3; kj++){
                float wv = w[ki*3 + kj];
                #pragma unroll
                for (int p = 0; p < 8; p++)
                    o[p] += wv * rw[kj + p];
            }
        }
        uint4 pk;
        pk.x = (u32)f2bf(o[0]) | ((u32)f2bf(o[1]) << 16);
        pk.y = (u32)f2bf(o[2]) | ((u32)f2bf(o[3]) << 16);
        pk.z = (u32)f2bf(o[4]) | ((u32)f2bf(o[5]) << 16);
        pk.w = (u32)f2bf(o[6]) | ((u32)f2bf(o[7]) << 16);
        *(uint4*)(qc + r*WD + q*8) = pk;
    }
}

// ---------------- K3: fc branch MFMA GEMM -> fws GROUP-MAJOR (b,12,hw,16) ----
__global__ __launch_bounds__(256) void k3_mfma(const u16* __restrict__ qkv,
                                               const uint4* __restrict__ atab,
                                               const float* __restrict__ b_fc,
                                               u16* __restrict__ fws){
    int b  = blockIdx.y;
    int n0 = blockIdx.x * 64;
    __shared__ float bfc[9];
    __shared__ __align__(16) u16 ot[64*200];
    int t = threadIdx.x;
    if (t < 9) bfc[t] = b_fc[t];
    for (int i = t; i < 64*100; i += 256) ((u32*)ot)[i] = 0u;
    __syncthreads();
    int wv = t >> 6, lane = t & 63;
    int lr = lane & 15, lk = lane >> 4;
    int nl = wv*16 + lr;
    const u16* rowp = qkv + (size_t)b*C3*HW + (size_t)(n0 + nl)*288;
    union U { uint4 q; bf16x8 v; };
    U bfr[9];
    #pragma unroll
    for (int kk = 0; kk < 9; kk++)
        bfr[kk].q = *(const uint4*)(rowp + kk*32 + lk*8);

    #pragma unroll
    for (int ct = 0; ct < 7; ct++){
        U a[9];
        #pragma unroll
        for (int kk = 0; kk < 9; kk++)
            a[kk].q = atab[(ct*9 + kk)*64 + lane];
        f32x4 acc;
        #pragma unroll
        for (int r = 0; r < 4; r++){
            int coD = ct*16 + lk*4 + r;
            acc[r] = (coD < 108) ? bfc[coD % 9] : 0.f;
        }
        #pragma unroll
        for (int kk = 0; kk < 9; kk++)
            acc = __builtin_amdgcn_mfma_f32_16x16x32_bf16(a[kk].v, bfr[kk].v, acc, 0, 0, 0);
        #pragma unroll
        for (int r = 0; r < 4; r++){
            int co = ct*16 + lk*4 + r;
            if (co < 108){
                int dg = co / 9, o = co - dg*9;
                int slot = dg*16 + o;
                int p  = slot >> 1;
                int ps = p ^ (nl & 7);
                ot[nl*200 + (ps << 1) + (slot & 1)] = f2bf(acc[r]);
            }
        }
    }
    __syncthreads();
    const u32* otp = (const u32*)ot;
    u32* dstb = (u32*)fws;
    for (int i = t; i < 64*96; i += 256){
        int dg = i >> 9, rem = i & 511, nn = rem >> 3, s8 = rem & 7;
        int s = dg*8 + s8;
        dstb[((size_t)(b*12 + dg)*HW + n0 + nn)*8 + s8] = otp[nn*100 + (s ^ (nn & 7))];
    }
}

// ---------------- K4: Gram via MFMA, direct global loads ---------------------
__global__ __launch_bounds__(256) void k4_mfma(const u16* __restrict__ qkv,
                                               float* __restrict__ gpart){
    int b = blockIdx.z, h = blockIdx.y;
    int t = threadIdx.x;
    int wv = t >> 6, lane = t & 63;
    int lr = lane & 15, lk = lane >> 4;
    int row = (lr < 12) ? lr : 11;
    size_t pxb = (size_t)blockIdx.x*1024 + wv*256;
    const u16* qb = qkv + ((size_t)b*C3 + h*CHD + row)*HW + pxb;
    const u16* kb = qkv + ((size_t)b*C3 + C + h*CHD + row)*HW + pxb;
    union U { uint4 q; bf16x8 v; };
    f32x4 gqk = (f32x4){0.f,0.f,0.f,0.f};
    f32x4 gqq = (f32x4){0.f,0.f,0.f,0.f};
    f32x4 gkk = (f32x4){0.f,0.f,0.f,0.f};
    #pragma unroll
    for (int s = 0; s < 8; s++){
        U aq, ak;
        aq.q = *(const uint4*)(qb + s*32 + lk*8);
        ak.q = *(const uint4*)(kb + s*32 + lk*8);
        gqk = __builtin_amdgcn_mfma_f32_16x16x32_bf16(aq.v, ak.v, gqk, 0, 0, 0);
        gqq = __builtin_amdgcn_mfma_f32_16x16x32_bf16(aq.v, aq.v, gqq, 0, 0, 0);
        gkk = __builtin_amdgcn_mfma_f32_16x16x32_bf16(ak.v, ak.v, gkk, 0, 0, 0);
    }
    __shared__ float red[4][168];
    for (int i = t; i < 4*168; i += 256) ((float*)red)[i] = 0.f;
    __syncthreads();
    #pragma unroll
    for (int r = 0; r < 4; r++){
        int c = lk*4 + r;
        if (lr < 12 && c < 12){
            red[wv][c*12 + lr] = gqk[r];
            if (lr == c){
                red[wv][144 + c] = gqq[r];
                red[wv][156 + c] = gkk[r];
            }
        }
    }
    __syncthreads();
    if (t < 168){
        float a = red[0][t] + red[1][t] + red[2][t] + red[3][t];
        gpart[(((size_t)b*NH + h)*25 + blockIdx.x)*168 + t] = a;
    }
}

// ---------------- K5: softmax + M = W_proj @ blockdiag(attn) -> Mhi/Mlo bf16 -
__global__ void k5_attn(const float* __restrict__ gpart, const float* __restrict__ esgg,
                        const float* __restrict__ temp, const float* __restrict__ w_proj,
                        u16* __restrict__ Mhib, u16* __restrict__ Mlob){
    int b = blockIdx.x;
    int t = threadIdx.x;
    __shared__ float G[NH][144];
    __shared__ float q2[NH][12], k2[NH][12];
    __shared__ float attn[NH][144];
    for (int i = t; i < NH*168; i += 256){
        int h = i / 168, e = i % 168;
        float a = 0.f;
        for (int ch = 0; ch < 25; ch++)
            a += gpart[(((size_t)b*NH + h)*25 + ch)*168 + e];
        if (e < 144)      G[h][e] = a;
        else if (e < 156) q2[h][e-144] = a;
        else              k2[h][e-156] = a;
    }
    __syncthreads();
    if (t < 96){
        int h = t / 12, c = t % 12;
        float rq  = 1.0f / fmaxf(sqrtf(q2[h][c]), 1e-12f);
        float tm  = temp[h];
        float egc = esgg[b*96 + h*12 + c];
        float lo[12];
        float mx = -1e30f;
        for (int d = 0; d < 12; d++){
            float rk = 1.0f / fmaxf(sqrtf(k2[h][d]), 1e-12f);
            float v = G[h][c*12 + d] * rq * rk * tm * (egc * esgg[b*96 + h*12 + d]);
            lo[d] = v;
            mx = fmaxf(mx, v);
        }
        float s = 0.f;
        for (int d = 0; d < 12; d++){ lo[d] = expf(lo[d] - mx); s += lo[d]; }
        float inv = 1.0f / s;
        for (int d = 0; d < 12; d++) attn[h][c*12 + d] = lo[d] * inv;
    }
    __syncthreads();
    for (int i = t; i < 96*96; i += 256){
        int co = i / 96, ci = i % 96;
        int h = ci / 12, d = ci % 12;
        float a = 0.f;
        #pragma unroll
        for (int c = 0; c < 12; c++)
            a += w_proj[co*96 + h*12 + c] * attn[h][c*12 + d];
        u16 hi = f2bf(a);
        float resid = a - bf2f(hi);
        Mhib[((size_t)b*96 + co)*96 + ci] = hi;
        Mlob[((size_t)b*96 + co)*96 + ci] = f2bf(resid);
    }
}

// ---------------- K6a: grouped 3x3 conv via MFMA, group-major fws ------------
#define CP6 24
__global__ __launch_bounds__(256) void k6a_iv(const u16* __restrict__ fws,
                                              const float* __restrict__ w_dep,
                                              const float* __restrict__ b_dep,
                                              float* __restrict__ out){
    int d = blockIdx.x, b = blockIdx.z;
    int ty = blockIdx.y / 5, tx = blockIdx.y % 5;     // 10 x 5 tiles of 16x32
    int r0 = ty*16, c0 = tx*32;
    __shared__ __align__(16) u16 inl[19*34*CP6];       // 31,008 B
    __shared__ __align__(16) u16 Wt2[16*160];          // 5,120 B
    int t = threadIdx.x;
    const uint4* fsrc = (const uint4*)fws;             // 2 uint4 per pixel
    for (int i = t; i < 646; i += 256){
        uint4 v0 = make_uint4(0,0,0,0), v1 = make_uint4(0,0,0,0);
        if (i < 612){
            int r = i / 34, c = i - r*34;
            int gr = r0 + r - 1, gc = c0 + c - 1;
            if (gr >= 0 && gr < HT && gc >= 0 && gc < WD){
                const uint4* src = fsrc + ((size_t)((b*12 + d)*HW + gr*WD + gc) * 2);
                v0 = src[0]; v1 = src[1];
            }
        }
        uint4* dstp = (uint4*)(&inl[i*CP6]);
        dstp[0] = v0; dstp[1] = v1;
    }
    for (int i = t; i < 16*160; i += 256){
        int row = i / 160, k = i % 160;
        int tap = k >> 4, chp = k & 15;
        float wv = (row < 8 && tap < 9 && chp < 9)
                   ? w_dep[(size_t)(d*8 + row)*81 + chp*9 + tap] : 0.f;
        Wt2[i] = f2bf(wv);
    }
    __syncthreads();
    int wv = t >> 6, lane = t & 63;
    int lr = lane & 15, lk = lane >> 4;
    union U { uint4 q; bf16x8 v; };
    bf16x8 afr[5];
    #pragma unroll
    for (int kk = 0; kk < 5; kk++){
        U u; u.q = *(const uint4*)(&Wt2[lr*160 + kk*32 + lk*8]);
        afr[kk] = u.v;
    }
    int tap0 = lk >> 1;
    int h8   = (lk & 1) * 8;
    float binit[4];
    #pragma unroll
    for (int r = 0; r < 4; r++) binit[r] = (lk < 2) ? b_dep[d*8 + lk*4 + r] : 0.f;

    for (int gi = 0; gi < 8; gi++){
        int g = wv*8 + gi;
        int ry = g >> 1, half = g & 1;
        int cpx = half*16 + lr;
        f32x4 acc = (f32x4){binit[0], binit[1], binit[2], binit[3]};
        #pragma unroll
        for (int kk = 0; kk < 5; kk++){
            int tap = kk*2 + tap0;                   // 0..9 (9 -> zero row 18)
            int ki = tap / 3, kj = tap - ki*3;
            U u; u.q = *(const uint4*)(&inl[((ry + ki)*34 + cpx + kj)*CP6 + h8]);
            acc = __builtin_amdgcn_mfma_f32_16x16x32_bf16(afr[kk], u.v, acc, 0, 0, 0);
        }
        if (lk < 2){
            #pragma unroll
            for (int r = 0; r < 4; r++){
                int oc = d*8 + lk*4 + r;
                out[((size_t)b*C + oc)*HW + (r0 + ry)*WD + c0 + cpx] = acc[r];
            }
        }
    }
}

// ---------------- K6b: out += M[b] @ V via MFMA (96 oc per block) ------------
__global__ __launch_bounds__(256) void k6b_mfma(const u16* __restrict__ qkv,
                                                const u16* __restrict__ Mhib,
                                                const u16* __restrict__ Mlob,
                                                float* __restrict__ out){
    int b   = blockIdx.y;
    int px0 = blockIdx.x * 64;
    __shared__ __align__(16) u16 Vl[64*128];
    int t = threadIdx.x;
    const u32* vsrc = (const u32*)(qkv + ((size_t)b*C3 + 2*C)*HW + px0);
    for (int i = t; i < 96*32; i += 256){
        int c = i >> 5, pq = i & 31;
        u32 v = vsrc[(size_t)c*(HW/2) + pq];
        int slot = (((c >> 3) ^ (pq & 7)) << 3) + (c & 7);
        Vl[(2*pq)*128 + slot]   = (u16)(v & 0xffffu);
        Vl[(2*pq+1)*128 + slot] = (u16)(v >> 16);
    }
    __syncthreads();
    int wid = t >> 6, lane = t & 63;
    int lr = lane & 15, lk = lane >> 4;
    union U { uint4 q; bf16x8 v; };
    int px = wid*16 + lr;
    int key = (px >> 1) & 7;
    bf16x8 bfr[3];
    #pragma unroll
    for (int kk = 0; kk < 3; kk++){
        int gs = (kk*4 + lk) ^ key;
        U u; u.q = *(const uint4*)(&Vl[px*128 + gs*8]);
        bfr[kk] = u.v;
    }
    const u16* mh = Mhib + (size_t)b*96*96;
    const u16* ml = Mlob + (size_t)b*96*96;
    for (int og = 0; og < 6; og++){
        int arow = og*16 + lr;
        f32x4 acc = (f32x4){0.f,0.f,0.f,0.f};
        #pragma unroll
        for (int kk = 0; kk < 3; kk++){
            U ah; ah.q = *(const uint4*)(mh + (size_t)arow*96 + kk*32 + lk*8);
            U al; al.q = *(const uint4*)(ml + (size_t)arow*96 + kk*32 + lk*8);
            acc = __builtin_amdgcn_mfma_f32_16x16x32_bf16(ah.v, bfr[kk], acc, 0, 0, 0);
            acc = __builtin_amdgcn_mfma_f32_16x16x32_bf16(al.v, bfr[kk], acc, 0, 0, 0);
        }
        #pragma unroll
        for (int r = 0; r < 4; r++){
            int oc = og*16 + lk*4 + r;
            float* op = out + ((size_t)b*C + oc)*HW + px0 + wid*16 + lr;
            *op += acc[r];
        }
    }
}

// -----------------------------------------------------------------------------
extern "C" void kernel_launch(void* const* d_in, const int* in_sizes, int n_in,
                              void* d_out, int out_size, void* d_ws, size_t ws_size,
                              hipStream_t stream){
    (void)in_sizes; (void)n_in; (void)out_size;
    const float* x           = (const float*)d_in[0];
    const float* spectral    = (const float*)d_in[1];
    const float* temperature = (const float*)d_in[2];
    const float* w_qkv       = (const float*)d_in[3];
    const float* w_dw        = (const float*)d_in[4];
    const float* w_proj      = (const float*)d_in[5];
    const float* w_fc        = (const float*)d_in[6];
    const float* b_fc        = (const float*)d_in[7];
    const float* w_dep       = (const float*)d_in[8];
    const float* b_dep       = (const float*)d_in[9];
    const float* w_se1       = (const float*)d_in[10];
    const float* b_se1       = (const float*)d_in[11];
    const float* w_se2       = (const float*)d_in[12];
    const float* b_se2       = (const float*)d_in[13];
    const float* w_saw1      = (const float*)d_in[14];
    const float* b_saw1      = (const float*)d_in[15];
    const float* w_saw2      = (const float*)d_in[16];
    const float* b_saw2      = (const float*)d_in[17];
    const float* w_sgp       = (const float*)d_in[18];
    const float* b_sgp       = (const float*)d_in[19];
    float* out = (float*)d_out;
    char* ws   = (char*)d_ws;

    const size_t QKV_B = 58982400ull;   // 4*288*25600 bf16
    const size_t Y4    = 58982400ull;   // full-batch Y
    const size_t Y1    = 14745600ull;   // one-batch Y
    const size_t FWS_B = 39321600ull;   // 4*12*25600*16 bf16 (group-major)
    const size_t XB_B  = 19660800ull;   // 4*96*25600 bf16
    const size_t SM_B  = 1000000ull;
    bool fullY = ws_size >= QKV_B + Y4 + XB_B + SM_B;

    u16 *qkv = (u16*)ws, *Y, *fws, *xb;
    float* sm;
    if (fullY){
        Y   = (u16*)(ws + QKV_B);
        fws = Y;
        xb  = (u16*)(ws + QKV_B + Y4);
        sm  = (float*)(ws + QKV_B + Y4 + XB_B);
    } else {
        Y   = (u16*)(ws + QKV_B);
        xb  = (u16*)(ws + QKV_B + Y1);
        fws = xb;
        sm  = (float*)(ws + QKV_B + Y1 + FWS_B);
    }
    float* xsum  = sm;            // 384
    float* swg   = sm + 384;      // 384
    float* esgg  = sm + 768;      // 384
    float* gpart = sm + 1152;     // 134,400  (ends at 135,552 floats)
    u16*   weffb = (u16*)(sm + 135552);            // 221,184 B
    u16*   Mhib  = (u16*)((char*)weffb + 221184);  // 73,728 B
    u16*   Mlob  = (u16*)((char*)Mhib + 73728);    // 73,728 B
    uint4* atab  = (uint4*)((char*)Mlob + 73728);  // 64,512 B (total 975,360 < 1 MB)

    k0_xsum <<<dim3(NB*C), dim3(256), 0, stream>>>(x, xsum, xb);
    k1_small<<<dim3(NB),   dim3(256), 0, stream>>>(spectral, xsum,
                w_se1, b_se1, w_se2, b_se2, w_saw1, b_saw1, w_saw2, b_saw2,
                w_sgp, b_sgp, swg, esgg);
    k1w_weff<<<dim3(NB,108), dim3(256), 0, stream>>>(w_qkv, swg, weffb);
    k3w_atab<<<dim3(1),      dim3(256), 0, stream>>>(w_fc, atab);
    if (fullY){
        k2a_mfma<<<dim3(400,NB), dim3(384), 0, stream>>>(xb, weffb, Y, 0, (long)C3*HW);
        k2b_dw  <<<dim3(10,C3,NB), dim3(256), 0, stream>>>(Y, w_dw, qkv, 0, (long)C3*HW);
    } else {
        for (int b = 0; b < NB; b++){
            k2a_mfma<<<dim3(400,1), dim3(384), 0, stream>>>(xb, weffb, Y, b, 0);
            k2b_dw  <<<dim3(10,C3,1), dim3(256), 0, stream>>>(Y, w_dw, qkv, b, 0);
        }
    }
    k3_mfma <<<dim3(400,NB),   dim3(256), 0, stream>>>(qkv, atab, b_fc, fws);
    k4_mfma <<<dim3(25,NH,NB), dim3(256), 0, stream>>>(qkv, gpart);
    k5_attn <<<dim3(NB),       dim3(256), 0, stream>>>(gpart, esgg, temperature, w_proj, Mhib, Mlob);
    k6a_iv  <<<dim3(12,50,NB), dim3(256), 0, stream>>>(fws, w_dep, b_dep, out);
    k6b_mfma<<<dim3(400,NB),   dim3(256), 0, stream>>>(qkv, Mhib, Mlob, out);
}

// Round 18
// 194.836 us; speedup vs baseline: 1.0776x; 1.0776x over previous
//
#include <hip/hip_runtime.h>
#include <math.h>

#define NB 4
#define C 96
#define C3 288
#define NH 8
#define CHD 12
#define HT 160
#define WD 160
#define HW 25600

typedef unsigned short u16;
typedef unsigned int   u32;
typedef __bf16 bf16x8 __attribute__((ext_vector_type(8)));
typedef float  f32x4  __attribute__((ext_vector_type(4)));

__device__ __forceinline__ float gelu_f(float x){
    return 0.5f * x * (1.0f + erff(x * 0.7071067811865475f));
}
__device__ __forceinline__ float sigmoid_f(float x){
    return 1.0f / (1.0f + expf(-x));
}
__device__ __forceinline__ u16 f2bf(float x){
    union { float f; u32 u; } v; v.f = x;
    u32 r = v.u + 0x7FFFu + ((v.u >> 16) & 1u);
    return (u16)(r >> 16);
}
__device__ __forceinline__ float bf2f(u16 s){
    union { u32 u; float f; } v; v.u = ((u32)s) << 16;
    return v.f;
}

// ---------------- K0: per-(b,c) spatial sums of x + bf16 copy of x ----------
__global__ __launch_bounds__(256) void k0_xsum(const float* __restrict__ x,
                                               float* __restrict__ xsum,
                                               u16* __restrict__ xb){
    int bc = blockIdx.x;                       // 0..383
    const float4* p4 = (const float4*)(x + (size_t)bc * HW);
    u32* xo = (u32*)(xb + (size_t)bc * HW);
    float s = 0.f;
    for (int i = threadIdx.x; i < HW/4; i += 256){
        float4 v = p4[i];
        s += (v.x + v.y) + (v.z + v.w);
        xo[i*2]   = (u32)f2bf(v.x) | ((u32)f2bf(v.y) << 16);
        xo[i*2+1] = (u32)f2bf(v.z) | ((u32)f2bf(v.w) << 16);
    }
    __shared__ float red[256];
    red[threadIdx.x] = s;
    __syncthreads();
    for (int off = 128; off > 0; off >>= 1){
        if (threadIdx.x < off) red[threadIdx.x] += red[threadIdx.x + off];
        __syncthreads();
    }
    if (threadIdx.x == 0) xsum[bc] = red[0];
}

// ---------------- K1: per-batch tiny math (one block per batch) --------------
__global__ void k1_small(const float* __restrict__ spectral, const float* __restrict__ xsum,
                         const float* __restrict__ w_se1, const float* __restrict__ b_se1,
                         const float* __restrict__ w_se2, const float* __restrict__ b_se2,
                         const float* __restrict__ w_saw1, const float* __restrict__ b_saw1,
                         const float* __restrict__ w_saw2, const float* __restrict__ b_saw2,
                         const float* __restrict__ w_sgp, const float* __restrict__ b_sgp,
                         float* __restrict__ swg, float* __restrict__ esgg){
    __shared__ float spec[96];
    __shared__ float h1[192];
    __shared__ float cm_s;
    __shared__ float g1[9][24];
    __shared__ float saw[8];
    __shared__ float redbuf[96];
    int t = threadIdx.x;
    int b = blockIdx.x;
    if (t < 96) spec[t] = spectral[b*96 + t];
    __syncthreads();
    if (t < 192){
        float a = b_se1[t];
        for (int c = 0; c < 96; c++) a += spec[c] * w_se1[t*96 + c];
        h1[t] = gelu_f(a);
    }
    __syncthreads();
    if (t < 96){
        float a = b_se2[t];
        for (int j = 0; j < 192; j++) a += h1[j] * w_se2[t*192 + j];
        float s = sigmoid_f(a);
        swg[b*96 + t] = s;
        redbuf[t] = s * xsum[b*96 + t];
    }
    __syncthreads();
    if (t == 0){
        float cs = 0.f;
        for (int c = 0; c < 96; c++) cs += redbuf[c];
        cm_s = cs / (96.0f * (float)HW);
    }
    __syncthreads();
    float cm = cm_s;
    if (t < 9*24){
        int cat = t / 24, ch = t % 24;
        int ti = cat / 3, tj = cat % 3;
        float S = 0.f;
        for (int ki = 0; ki < 3; ki++){
            if (ti == 0 && ki == 0) continue;
            if (ti == 2 && ki == 2) continue;
            for (int kj = 0; kj < 3; kj++){
                if (tj == 0 && kj == 0) continue;
                if (tj == 2 && kj == 2) continue;
                S += w_saw1[ch*9 + ki*3 + kj];
            }
        }
        g1[cat][ch] = gelu_f(cm * S + b_saw1[ch]);
    }
    __syncthreads();
    if (t < 8){
        float acc = 0.f;
        const float cnt[3] = {1.f, 158.f, 1.f};
        for (int cat = 0; cat < 9; cat++){
            float a = b_saw2[t];
            for (int ch = 0; ch < 24; ch++) a += w_saw2[t*24 + ch] * g1[cat][ch];
            acc += cnt[cat/3] * cnt[cat%3] * sigmoid_f(a);
        }
        saw[t] = acc / (float)HW;
    }
    __syncthreads();
    if (t < 96){
        float a = b_sgp[t];
        for (int j = 0; j < 96; j++) a += spec[j] * w_sgp[t*96 + j];
        esgg[b*96 + t] = a * saw[t/12];
    }
}

// ---------------- K1w: bake weffb = bf16(w_qkv * sw[b]) ----------------------
__global__ __launch_bounds__(256) void k1w_weff(const float* __restrict__ w_qkv,
                                                const float* __restrict__ swg,
                                                u16* __restrict__ weffb){
    int b = blockIdx.x;
    int i = blockIdx.y * 256 + threadIdx.x;     // 0..27647
    float w = w_qkv[i] * swg[b*96 + (i % 96)];
    weffb[(size_t)b*C3*96 + i] = f2bf(w);
}

// ---------------- K3w: precompute k3's structured A-fragment table -----------
__global__ __launch_bounds__(256) void k3w_atab(const float* __restrict__ w_fc,
                                                uint4* __restrict__ atab){
    for (int idx = threadIdx.x; idx < 63*64; idx += 256){
        int ct = idx / (9*64), rem = idx % (9*64);
        int kk = rem / 64, lane = rem % 64;
        int lr = lane & 15, lk = lane >> 4;
        int coA = ct*16 + lr;
        int dA = coA / 9;
        int oA = coA - dA*9;
        int base = kk*32 + lk*8;
        int bm = base % 12;
        int slot = dA - bm; slot += (slot < 0) ? 12 : 0;
        int j = base + slot;
        float wvl = (coA < 108 && slot < 8) ? w_fc[oA*24 + j/12] : 0.f;
        u32 pk = ((u32)f2bf(wvl)) << ((slot & 1) * 16);
        int sh = slot >> 1;
        uint4 a;
        a.x = (sh == 0) ? pk : 0u;
        a.y = (sh == 1) ? pk : 0u;
        a.z = (sh == 2) ? pk : 0u;
        a.w = (sh == 3) ? pk : 0u;
        atab[idx] = a;
    }
}

// ---------------- K2a: MFMA 1x1 conv, full 288 oc per block ------------------
__global__ __launch_bounds__(384) void k2a_mfma(const u16* __restrict__ xb,
                                                const u16* __restrict__ weffb,
                                                u16* __restrict__ Y,
                                                int bbase, long ystride){
    int b   = bbase + blockIdx.y;
    int px0 = blockIdx.x * 64;
    __shared__ __align__(16) u16 Xl[64*128];
    int t = threadIdx.x;
    const u32* xsrc = (const u32*)(xb + (size_t)b*C*HW + px0);
    for (int i = t; i < 96*32; i += 384){
        int c = i >> 5, pq = i & 31;
        u32 v = xsrc[(size_t)c*(HW/2) + pq];
        int slot = (((c >> 3) ^ (pq & 7)) << 3) + (c & 7);
        Xl[(2*pq)*128 + slot]     = (u16)(v & 0xffffu);
        Xl[(2*pq+1)*128 + slot]   = (u16)(v >> 16);
    }
    int wid = t >> 6, lane = t & 63;
    int lr = lane & 15, lk = lane >> 4;
    union U { uint4 q; bf16x8 v; };
    bf16x8 afr[3][3];
    const u16* wb = weffb + (size_t)b*C3*96;
    #pragma unroll
    for (int og = 0; og < 3; og++){
        int oc = og*96 + wid*16 + lr;
        #pragma unroll
        for (int kk = 0; kk < 3; kk++){
            U u; u.q = *(const uint4*)(wb + (size_t)oc*96 + kk*32 + lk*8);
            afr[og][kk] = u.v;
        }
    }
    __syncthreads();
    u16* Yb = Y + (size_t)blockIdx.y * ystride;
    #pragma unroll
    for (int sub = 0; sub < 4; sub++){
        int px = sub*16 + lr;
        int key = (px >> 1) & 7;
        bf16x8 bfr[3];
        #pragma unroll
        for (int kk = 0; kk < 3; kk++){
            int gs = (kk*4 + lk) ^ key;
            U u; u.q = *(const uint4*)(&Xl[px*128 + gs*8]);
            bfr[kk] = u.v;
        }
        #pragma unroll
        for (int og = 0; og < 3; og++){
            f32x4 acc = (f32x4){0.f,0.f,0.f,0.f};
            #pragma unroll
            for (int kk = 0; kk < 3; kk++)
                acc = __builtin_amdgcn_mfma_f32_16x16x32_bf16(afr[og][kk], bfr[kk], acc, 0, 0, 0);
            #pragma unroll
            for (int r = 0; r < 4; r++){
                int oc = og*96 + wid*16 + lk*4 + r;
                Yb[(size_t)oc*HW + px0 + sub*16 + lr] = f2bf(acc[r]);
            }
        }
    }
}

// ---------------- K2b: 3x3 depthwise, 16-row tiles, stride-172 f32 tile ------
// stride 172 (= 12 mod 32 banks) + row-major lane mapping -> conflict-free.
__global__ __launch_bounds__(256) void k2b_dw(const u16* __restrict__ Y,
                                              const float* __restrict__ w_dw,
                                              u16* __restrict__ qkv,
                                              int bbase, long ystride){
    int b  = bbase + blockIdx.z;
    int ch = blockIdx.y;
    int r0 = blockIdx.x * 16;                  // 10 x-blocks
    __shared__ float tile[18][172];
    const u16* Yc = Y + (size_t)blockIdx.z*ystride + (size_t)ch*HW;
    int t = threadIdx.x;
    if (t < 18){ tile[t][3] = 0.f; tile[t][164] = 0.f; }
    for (int i = t; i < 360; i += 256){
        int r = i % 18, q = i / 18;
        int gr = r0 + r - 1;
        uint4 v = make_uint4(0,0,0,0);
        if (gr >= 0 && gr < HT) v = *(const uint4*)(Yc + gr*WD + q*8);
        float* dst = &tile[r][4 + q*8];
        float4 f0 = make_float4(bf2f((u16)(v.x & 0xffffu)), bf2f((u16)(v.x >> 16)),
                                bf2f((u16)(v.y & 0xffffu)), bf2f((u16)(v.y >> 16)));
        float4 f1 = make_float4(bf2f((u16)(v.z & 0xffffu)), bf2f((u16)(v.z >> 16)),
                                bf2f((u16)(v.w & 0xffffu)), bf2f((u16)(v.w >> 16)));
        *(float4*)(dst)     = f0;
        *(float4*)(dst + 4) = f1;
    }
    float w[9];
    #pragma unroll
    for (int k = 0; k < 9; k++) w[k] = w_dw[ch*9 + k];
    __syncthreads();
    u16* qc = qkv + ((size_t)b*C3 + ch)*HW + r0*WD;
    for (int i = t; i < 320; i += 256){
        int r = i & 15, q = i >> 4;            // row-major lanes: r varies fastest
        float o[8];
        #pragma unroll
        for (int p = 0; p < 8; p++) o[p] = 0.f;
        #pragma unroll
        for (int ki = 0; ki < 3; ki++){
            const float* row = &tile[r + ki][q*8];
            float rw[10];
            rw[0] = row[3];
            float4 A = *(const float4*)(row + 4);
            float4 B = *(const float4*)(row + 8);
            rw[1]=A.x; rw[2]=A.y; rw[3]=A.z; rw[4]=A.w;
            rw[5]=B.x; rw[6]=B.y; rw[7]=B.z; rw[8]=B.w;
            rw[9] = row[12];
            #pragma unroll
            for (int kj = 0; kj < 3; kj++){
                float wv = w[ki*3 + kj];
                #pragma unroll
                for (int p = 0; p < 8; p++)
                    o[p] += wv * rw[kj + p];
            }
        }
        uint4 pk;
        pk.x = (u32)f2bf(o[0]) | ((u32)f2bf(o[1]) << 16);
        pk.y = (u32)f2bf(o[2]) | ((u32)f2bf(o[3]) << 16);
        pk.z = (u32)f2bf(o[4]) | ((u32)f2bf(o[5]) << 16);
        pk.w = (u32)f2bf(o[6]) | ((u32)f2bf(o[7]) << 16);
        *(uint4*)(qc + r*WD + q*8) = pk;
    }
}

// ---------------- K3: fc branch MFMA GEMM -> fws GROUP-MAJOR (b,12,hw,16) ----
__global__ __launch_bounds__(256) void k3_mfma(const u16* __restrict__ qkv,
                                               const uint4* __restrict__ atab,
                                               const float* __restrict__ b_fc,
                                               u16* __restrict__ fws){
    int b  = blockIdx.y;
    int n0 = blockIdx.x * 64;
    __shared__ float bfc[9];
    __shared__ __align__(16) u16 ot[64*200];
    int t = threadIdx.x;
    if (t < 9) bfc[t] = b_fc[t];
    for (int i = t; i < 64*100; i += 256) ((u32*)ot)[i] = 0u;
    __syncthreads();
    int wv = t >> 6, lane = t & 63;
    int lr = lane & 15, lk = lane >> 4;
    int nl = wv*16 + lr;
    const u16* rowp = qkv + (size_t)b*C3*HW + (size_t)(n0 + nl)*288;
    union U { uint4 q; bf16x8 v; };
    U bfr[9];
    #pragma unroll
    for (int kk = 0; kk < 9; kk++)
        bfr[kk].q = *(const uint4*)(rowp + kk*32 + lk*8);

    #pragma unroll
    for (int ct = 0; ct < 7; ct++){
        U a[9];
        #pragma unroll
        for (int kk = 0; kk < 9; kk++)
            a[kk].q = atab[(ct*9 + kk)*64 + lane];
        f32x4 acc;
        #pragma unroll
        for (int r = 0; r < 4; r++){
            int coD = ct*16 + lk*4 + r;
            acc[r] = (coD < 108) ? bfc[coD % 9] : 0.f;
        }
        #pragma unroll
        for (int kk = 0; kk < 9; kk++)
            acc = __builtin_amdgcn_mfma_f32_16x16x32_bf16(a[kk].v, bfr[kk].v, acc, 0, 0, 0);
        #pragma unroll
        for (int r = 0; r < 4; r++){
            int co = ct*16 + lk*4 + r;
            if (co < 108){
                int dg = co / 9, o = co - dg*9;
                int slot = dg*16 + o;
                int p  = slot >> 1;
                int ps = p ^ (nl & 7);
                ot[nl*200 + (ps << 1) + (slot & 1)] = f2bf(acc[r]);
            }
        }
    }
    __syncthreads();
    const u32* otp = (const u32*)ot;
    u32* dstb = (u32*)fws;
    for (int i = t; i < 64*96; i += 256){
        int dg = i >> 9, rem = i & 511, nn = rem >> 3, s8 = rem & 7;
        int s = dg*8 + s8;
        dstb[((size_t)(b*12 + dg)*HW + n0 + nn)*8 + s8] = otp[nn*100 + (s ^ (nn & 7))];
    }
}

// ---------------- K4: Gram via MFMA, direct global loads ---------------------
__global__ __launch_bounds__(256) void k4_mfma(const u16* __restrict__ qkv,
                                               float* __restrict__ gpart){
    int b = blockIdx.z, h = blockIdx.y;
    int t = threadIdx.x;
    int wv = t >> 6, lane = t & 63;
    int lr = lane & 15, lk = lane >> 4;
    int row = (lr < 12) ? lr : 11;
    size_t pxb = (size_t)blockIdx.x*1024 + wv*256;
    const u16* qb = qkv + ((size_t)b*C3 + h*CHD + row)*HW + pxb;
    const u16* kb = qkv + ((size_t)b*C3 + C + h*CHD + row)*HW + pxb;
    union U { uint4 q; bf16x8 v; };
    f32x4 gqk = (f32x4){0.f,0.f,0.f,0.f};
    f32x4 gqq = (f32x4){0.f,0.f,0.f,0.f};
    f32x4 gkk = (f32x4){0.f,0.f,0.f,0.f};
    #pragma unroll
    for (int s = 0; s < 8; s++){
        U aq, ak;
        aq.q = *(const uint4*)(qb + s*32 + lk*8);
        ak.q = *(const uint4*)(kb + s*32 + lk*8);
        gqk = __builtin_amdgcn_mfma_f32_16x16x32_bf16(aq.v, ak.v, gqk, 0, 0, 0);
        gqq = __builtin_amdgcn_mfma_f32_16x16x32_bf16(aq.v, aq.v, gqq, 0, 0, 0);
        gkk = __builtin_amdgcn_mfma_f32_16x16x32_bf16(ak.v, ak.v, gkk, 0, 0, 0);
    }
    __shared__ float red[4][168];
    for (int i = t; i < 4*168; i += 256) ((float*)red)[i] = 0.f;
    __syncthreads();
    #pragma unroll
    for (int r = 0; r < 4; r++){
        int c = lk*4 + r;
        if (lr < 12 && c < 12){
            red[wv][c*12 + lr] = gqk[r];
            if (lr == c){
                red[wv][144 + c] = gqq[r];
                red[wv][156 + c] = gkk[r];
            }
        }
    }
    __syncthreads();
    if (t < 168){
        float a = red[0][t] + red[1][t] + red[2][t] + red[3][t];
        gpart[(((size_t)b*NH + h)*25 + blockIdx.x)*168 + t] = a;
    }
}

// ---------------- K5: softmax + M = W_proj @ blockdiag(attn) -> Mhi/Mlo bf16 -
__global__ void k5_attn(const float* __restrict__ gpart, const float* __restrict__ esgg,
                        const float* __restrict__ temp, const float* __restrict__ w_proj,
                        u16* __restrict__ Mhib, u16* __restrict__ Mlob){
    int b = blockIdx.x;
    int t = threadIdx.x;
    __shared__ float G[NH][144];
    __shared__ float q2[NH][12], k2[NH][12];
    __shared__ float attn[NH][144];
    for (int i = t; i < NH*168; i += 256){
        int h = i / 168, e = i % 168;
        float a = 0.f;
        for (int ch = 0; ch < 25; ch++)
            a += gpart[(((size_t)b*NH + h)*25 + ch)*168 + e];
        if (e < 144)      G[h][e] = a;
        else if (e < 156) q2[h][e-144] = a;
        else              k2[h][e-156] = a;
    }
    __syncthreads();
    if (t < 96){
        int h = t / 12, c = t % 12;
        float rq  = 1.0f / fmaxf(sqrtf(q2[h][c]), 1e-12f);
        float tm  = temp[h];
        float egc = esgg[b*96 + h*12 + c];
        float lo[12];
        float mx = -1e30f;
        for (int d = 0; d < 12; d++){
            float rk = 1.0f / fmaxf(sqrtf(k2[h][d]), 1e-12f);
            float v = G[h][c*12 + d] * rq * rk * tm * (egc * esgg[b*96 + h*12 + d]);
            lo[d] = v;
            mx = fmaxf(mx, v);
        }
        float s = 0.f;
        for (int d = 0; d < 12; d++){ lo[d] = expf(lo[d] - mx); s += lo[d]; }
        float inv = 1.0f / s;
        for (int d = 0; d < 12; d++) attn[h][c*12 + d] = lo[d] * inv;
    }
    __syncthreads();
    for (int i = t; i < 96*96; i += 256){
        int co = i / 96, ci = i % 96;
        int h = ci / 12, d = ci % 12;
        float a = 0.f;
        #pragma unroll
        for (int c = 0; c < 12; c++)
            a += w_proj[co*96 + h*12 + c] * attn[h][c*12 + d];
        u16 hi = f2bf(a);
        float resid = a - bf2f(hi);
        Mhib[((size_t)b*96 + co)*96 + ci] = hi;
        Mlob[((size_t)b*96 + co)*96 + ci] = f2bf(resid);
    }
}

// ---------------- K6a: grouped 3x3 conv via MFMA, group-major fws ------------
#define CP6 24
__global__ __launch_bounds__(256) void k6a_iv(const u16* __restrict__ fws,
                                              const float* __restrict__ w_dep,
                                              const float* __restrict__ b_dep,
                                              float* __restrict__ out){
    int d = blockIdx.x, b = blockIdx.z;
    int ty = blockIdx.y / 5, tx = blockIdx.y % 5;     // 10 x 5 tiles of 16x32
    int r0 = ty*16, c0 = tx*32;
    __shared__ __align__(16) u16 inl[19*34*CP6];       // 31,008 B
    __shared__ __align__(16) u16 Wt2[16*160];          // 5,120 B
    int t = threadIdx.x;
    const uint4* fsrc = (const uint4*)fws;             // 2 uint4 per pixel
    for (int i = t; i < 646; i += 256){
        uint4 v0 = make_uint4(0,0,0,0), v1 = make_uint4(0,0,0,0);
        if (i < 612){
            int r = i / 34, c = i - r*34;
            int gr = r0 + r - 1, gc = c0 + c - 1;
            if (gr >= 0 && gr < HT && gc >= 0 && gc < WD){
                const uint4* src = fsrc + ((size_t)((b*12 + d)*HW + gr*WD + gc) * 2);
                v0 = src[0]; v1 = src[1];
            }
        }
        uint4* dstp = (uint4*)(&inl[i*CP6]);
        dstp[0] = v0; dstp[1] = v1;
    }
    for (int i = t; i < 16*160; i += 256){
        int row = i / 160, k = i % 160;
        int tap = k >> 4, chp = k & 15;
        float wv = (row < 8 && tap < 9 && chp < 9)
                   ? w_dep[(size_t)(d*8 + row)*81 + chp*9 + tap] : 0.f;
        Wt2[i] = f2bf(wv);
    }
    __syncthreads();
    int wv = t >> 6, lane = t & 63;
    int lr = lane & 15, lk = lane >> 4;
    union U { uint4 q; bf16x8 v; };
    bf16x8 afr[5];
    #pragma unroll
    for (int kk = 0; kk < 5; kk++){
        U u; u.q = *(const uint4*)(&Wt2[lr*160 + kk*32 + lk*8]);
        afr[kk] = u.v;
    }
    int tap0 = lk >> 1;
    int h8   = (lk & 1) * 8;
    float binit[4];
    #pragma unroll
    for (int r = 0; r < 4; r++) binit[r] = (lk < 2) ? b_dep[d*8 + lk*4 + r] : 0.f;

    for (int gi = 0; gi < 8; gi++){
        int g = wv*8 + gi;
        int ry = g >> 1, half = g & 1;
        int cpx = half*16 + lr;
        f32x4 acc = (f32x4){binit[0], binit[1], binit[2], binit[3]};
        #pragma unroll
        for (int kk = 0; kk < 5; kk++){
            int tap = kk*2 + tap0;                   // 0..9 (9 -> zero row 18)
            int ki = tap / 3, kj = tap - ki*3;
            U u; u.q = *(const uint4*)(&inl[((ry + ki)*34 + cpx + kj)*CP6 + h8]);
            acc = __builtin_amdgcn_mfma_f32_16x16x32_bf16(afr[kk], u.v, acc, 0, 0, 0);
        }
        if (lk < 2){
            #pragma unroll
            for (int r = 0; r < 4; r++){
                int oc = d*8 + lk*4 + r;
                out[((size_t)b*C + oc)*HW + (r0 + ry)*WD + c0 + cpx] = acc[r];
            }
        }
    }
}

// ---------------- K6b: out += M[b] @ V via MFMA (96 oc per block) ------------
__global__ __launch_bounds__(256) void k6b_mfma(const u16* __restrict__ qkv,
                                                const u16* __restrict__ Mhib,
                                                const u16* __restrict__ Mlob,
                                                float* __restrict__ out){
    int b   = blockIdx.y;
    int px0 = blockIdx.x * 64;
    __shared__ __align__(16) u16 Vl[64*128];
    int t = threadIdx.x;
    const u32* vsrc = (const u32*)(qkv + ((size_t)b*C3 + 2*C)*HW + px0);
    for (int i = t; i < 96*32; i += 256){
        int c = i >> 5, pq = i & 31;
        u32 v = vsrc[(size_t)c*(HW/2) + pq];
        int slot = (((c >> 3) ^ (pq & 7)) << 3) + (c & 7);
        Vl[(2*pq)*128 + slot]   = (u16)(v & 0xffffu);
        Vl[(2*pq+1)*128 + slot] = (u16)(v >> 16);
    }
    __syncthreads();
    int wid = t >> 6, lane = t & 63;
    int lr = lane & 15, lk = lane >> 4;
    union U { uint4 q; bf16x8 v; };
    int px = wid*16 + lr;
    int key = (px >> 1) & 7;
    bf16x8 bfr[3];
    #pragma unroll
    for (int kk = 0; kk < 3; kk++){
        int gs = (kk*4 + lk) ^ key;
        U u; u.q = *(const uint4*)(&Vl[px*128 + gs*8]);
        bfr[kk] = u.v;
    }
    const u16* mh = Mhib + (size_t)b*96*96;
    const u16* ml = Mlob + (size_t)b*96*96;
    for (int og = 0; og < 6; og++){
        int arow = og*16 + lr;
        f32x4 acc = (f32x4){0.f,0.f,0.f,0.f};
        #pragma unroll
        for (int kk = 0; kk < 3; kk++){
            U ah; ah.q = *(const uint4*)(mh + (size_t)arow*96 + kk*32 + lk*8);
            U al; al.q = *(const uint4*)(ml + (size_t)arow*96 + kk*32 + lk*8);
            acc = __builtin_amdgcn_mfma_f32_16x16x32_bf16(ah.v, bfr[kk], acc, 0, 0, 0);
            acc = __builtin_amdgcn_mfma_f32_16x16x32_bf16(al.v, bfr[kk], acc, 0, 0, 0);
        }
        #pragma unroll
        for (int r = 0; r < 4; r++){
            int oc = og*16 + lk*4 + r;
            float* op = out + ((size_t)b*C + oc)*HW + px0 + wid*16 + lr;
            *op += acc[r];
        }
    }
}

// -----------------------------------------------------------------------------
extern "C" void kernel_launch(void* const* d_in, const int* in_sizes, int n_in,
                              void* d_out, int out_size, void* d_ws, size_t ws_size,
                              hipStream_t stream){
    (void)in_sizes; (void)n_in; (void)out_size;
    const float* x           = (const float*)d_in[0];
    const float* spectral    = (const float*)d_in[1];
    const float* temperature = (const float*)d_in[2];
    const float* w_qkv       = (const float*)d_in[3];
    const float* w_dw        = (const float*)d_in[4];
    const float* w_proj      = (const float*)d_in[5];
    const float* w_fc        = (const float*)d_in[6];
    const float* b_fc        = (const float*)d_in[7];
    const float* w_dep       = (const float*)d_in[8];
    const float* b_dep       = (const float*)d_in[9];
    const float* w_se1       = (const float*)d_in[10];
    const float* b_se1       = (const float*)d_in[11];
    const float* w_se2       = (const float*)d_in[12];
    const float* b_se2       = (const float*)d_in[13];
    const float* w_saw1      = (const float*)d_in[14];
    const float* b_saw1      = (const float*)d_in[15];
    const float* w_saw2      = (const float*)d_in[16];
    const float* b_saw2      = (const float*)d_in[17];
    const float* w_sgp       = (const float*)d_in[18];
    const float* b_sgp       = (const float*)d_in[19];
    float* out = (float*)d_out;
    char* ws   = (char*)d_ws;

    const size_t QKV_B = 58982400ull;   // 4*288*25600 bf16
    const size_t Y4    = 58982400ull;   // full-batch Y
    const size_t Y1    = 14745600ull;   // one-batch Y
    const size_t FWS_B = 39321600ull;   // 4*12*25600*16 bf16 (group-major)
    const size_t XB_B  = 19660800ull;   // 4*96*25600 bf16
    const size_t SM_B  = 1000000ull;
    bool fullY = ws_size >= QKV_B + Y4 + XB_B + SM_B;

    u16 *qkv = (u16*)ws, *Y, *fws, *xb;
    float* sm;
    if (fullY){
        Y   = (u16*)(ws + QKV_B);
        fws = Y;
        xb  = (u16*)(ws + QKV_B + Y4);
        sm  = (float*)(ws + QKV_B + Y4 + XB_B);
    } else {
        Y   = (u16*)(ws + QKV_B);
        xb  = (u16*)(ws + QKV_B + Y1);
        fws = xb;
        sm  = (float*)(ws + QKV_B + Y1 + FWS_B);
    }
    float* xsum  = sm;            // 384
    float* swg   = sm + 384;      // 384
    float* esgg  = sm + 768;      // 384
    float* gpart = sm + 1152;     // 134,400  (ends at 135,552 floats)
    u16*   weffb = (u16*)(sm + 135552);            // 221,184 B
    u16*   Mhib  = (u16*)((char*)weffb + 221184);  // 73,728 B
    u16*   Mlob  = (u16*)((char*)Mhib + 73728);    // 73,728 B
    uint4* atab  = (uint4*)((char*)Mlob + 73728);  // 64,512 B (total 975,360 < 1 MB)

    k0_xsum <<<dim3(NB*C), dim3(256), 0, stream>>>(x, xsum, xb);
    k1_small<<<dim3(NB),   dim3(256), 0, stream>>>(spectral, xsum,
                w_se1, b_se1, w_se2, b_se2, w_saw1, b_saw1, w_saw2, b_saw2,
                w_sgp, b_sgp, swg, esgg);
    k1w_weff<<<dim3(NB,108), dim3(256), 0, stream>>>(w_qkv, swg, weffb);
    k3w_atab<<<dim3(1),      dim3(256), 0, stream>>>(w_fc, atab);
    if (fullY){
        k2a_mfma<<<dim3(400,NB), dim3(384), 0, stream>>>(xb, weffb, Y, 0, (long)C3*HW);
        k2b_dw  <<<dim3(10,C3,NB), dim3(256), 0, stream>>>(Y, w_dw, qkv, 0, (long)C3*HW);
    } else {
        for (int b = 0; b < NB; b++){
            k2a_mfma<<<dim3(400,1), dim3(384), 0, stream>>>(xb, weffb, Y, b, 0);
            k2b_dw  <<<dim3(10,C3,1), dim3(256), 0, stream>>>(Y, w_dw, qkv, b, 0);
        }
    }
    k3_mfma <<<dim3(400,NB),   dim3(256), 0, stream>>>(qkv, atab, b_fc, fws);
    k4_mfma <<<dim3(25,NH,NB), dim3(256), 0, stream>>>(qkv, gpart);
    k5_attn <<<dim3(NB),       dim3(256), 0, stream>>>(gpart, esgg, temperature, w_proj, Mhib, Mlob);
    k6a_iv  <<<dim3(12,50,NB), dim3(256), 0, stream>>>(fws, w_dep, b_dep, out);
    k6b_mfma<<<dim3(400,NB),   dim3(256), 0, stream>>>(qkv, Mhib, Mlob, out);
}